// Round 8
// baseline (639.120 us; speedup 1.0000x reference)
//
#include <hip/hip_runtime.h>

// GR4J daily hydrological model, round 14: exact-pr two-kernel split.
// T=4015 steps, WARMUP=365, B=2048 basins.
//
// R13 (cold-start re-warmup, W=365) FAILED absmax 0.547: the production
// store s (capacity x1<=1200 vs ~0.3/day fluxes) has multi-thousand-day
// memory; 365 steps don't mix it. But ONLY the s-chain needs full serial
// depth: pr depends on s alone; conv is FIR; the routing store r forgets
// via outflow ~rx^4 (W=1825 -> residual ~<=0.006 in q); conv history is
// 6 taps and can be initialized EXACTLY from stored pr.
//
// Kernel A (32 blk x 128 thr): R12's staging + prod_step VERBATIM
//   (bit-identical pr), storing all 4015 pr rows to d_ws (32.9 MB).
//   No conv, no r, no output stores.
// Kernel B (320 blk x 128 thr, tj = blockIdx>>5 in 0..9): conv+r fused
//   in one wave, replaying from exact pr.
//   t_w0 = 0 for tj<=4 (blocks are BIT-IDENTICAL to the reference
//   trajectory, incl. the t=365 conv-history reset), 365*(tj-4) for
//   tj>=5 (exact conv-hist init from ws; r re-warmed 1825 steps from
//   r=0.5*x3 -- the ONLY approximation in the design).
//   Output rows [365*tj, 365*tj+365) written exactly once by exactly one
//   block: the R12 dump-row WAW hack and its vmcnt(0) drains are gone.
//
// This round also discriminates the two surviving perf models via A's
// dur: shared-issue (Sum x ~2cyc) predicts A ~115 us; lone-wave
// ~4.7cyc/inst predicts A ~235 us. B is ~55-85 us under both.
//
// Approximations (threshold 3.97e-2; R12 base absmax 7.8e-3):
//  - tanh(x) ~= x for x<=0.01; (1+z)^(-1/4) 3-term series in prod;
//  - rpe = 1/(dp*de) ~= 1-u+u^2, u = dp+de-2 (err ~1e-4);
//  - routing (1+zt)^(-1/8) deg-9 Taylor about 0.7 on [0,1.4];
//  - tj>=5 r-init error after 1825-step re-warmup (est. <=0.006).

#define T_TOTAL 4015
#define NWARM   365
#define NB      2048
#define CH      5           // pipeline chunk: 5 steps
#define NCHA    803         // kernel A chunks: 803*5 = 4015

typedef __attribute__((address_space(3))) float       lds_f;
typedef __attribute__((address_space(1))) const float glb_f;

__device__ __forceinline__ void gl_lds_16(const float* g, float* l) {
    // async global->LDS, 16B per active lane; LDS dst = uniform base + lane*16
    __builtin_amdgcn_global_load_lds((glb_f*)(uintptr_t)g,
                                     (lds_f*)(uintptr_t)l, 16, 0, 0);
}

__device__ __forceinline__ int ld_acq(int* p) {
    return __hip_atomic_load(p, __ATOMIC_ACQUIRE, __HIP_MEMORY_SCOPE_WORKGROUP);
}
__device__ __forceinline__ void st_rlx(int* p, int v) {
    __hip_atomic_store(p, v, __ATOMIC_RELAXED, __HIP_MEMORY_SCOPE_WORKGROUP);
}

// ======================= kernel A: serial s-pass =======================
__global__ __launch_bounds__(128, 1)
void gr4j_a(const float2* __restrict__ pe_in,   // [T_TOTAL*NB] (p,e)
            const float*  __restrict__ params,  // [NB,4]
            float*        __restrict__ prw)     // [T_TOTAL*NB] pr out (ws)
{
    const int lane = threadIdx.x & 63;
    const int wid  = threadIdx.x >> 6;
    const int b    = blockIdx.x * 64 + lane;

    __shared__ float4 inbuf[4][CH][32];          // 10.2 KB input ring
    __shared__ int in_ready;
    __shared__ int w1_done;
    if (threadIdx.x == 0) { in_ready = 0; w1_done = 0; }
    __syncthreads();   // the only barrier: flag init

    if (wid == 0) {
        // w0: input staging. 32 lanes x float4 = one row (64 (p,e) pairs).
        const float4* p4 = (const float4*)pe_in + (size_t)blockIdx.x * 32 + lane;
        const bool active = (lane < 32);
        if (active) {
            #pragma unroll
            for (int cc = 0; cc < 2; ++cc)
                #pragma unroll
                for (int i = 0; i < CH; ++i)
                    gl_lds_16((const float*)(p4 + (size_t)(cc * CH + i) * 1024),
                              (float*)&inbuf[cc][i][0]);
        }
        for (int c = 0; c <= NCHA - 3; ++c) {
            if (c >= 2) while (ld_acq(&w1_done) < c - 1) {}
            if (active) {
                const int slot = (c + 2) & 3;
                const float4* cb = p4 + (size_t)(c + 2) * CH * 1024;
                #pragma unroll
                for (int i = 0; i < CH; ++i)
                    gl_lds_16((const float*)(cb + (size_t)i * 1024),
                              (float*)&inbuf[slot][i][0]);
            }
            asm volatile("s_waitcnt vmcnt(5)" ::: "memory");
            if (lane == 0) st_rlx(&in_ready, c + 2);
        }
        asm volatile("s_waitcnt vmcnt(0)" ::: "memory");
        if (lane == 0) st_rlx(&in_ready, NCHA);
    } else {
        // w1: s-chain (R12 prod_step verbatim) -> pr stores to ws.
        const float x1 = 100.0f + params[b * 4 + 0] * 1100.0f;
        const float invx1 = __builtin_amdgcn_rcpf(x1);
        const float c49   = (4.0f / 9.0f) * invx1;
        const float c49_2 = c49 * c49;
        const float c4s   = c49_2 * c49_2;       // ((4/9)/x1)^4
        float s = 0.5f * x1;

        auto prod_step = [&](float p_, float e_) -> float {
            const float diff = p_ - e_;
            const float pn = fmaxf(diff, 0.0f);
            const float en = fmaxf(-diff, 0.0f);
            const float ap = pn * invx1;         // ~= tanh(pn/x1)
            const float ae = en * invx1;         // ~= tanh(en/x1)
            const float sx = s * invx1;
            const float omsx = 1.0f - sx;
            const float dp = fmaf(sx, ap, 1.0f);
            const float de = fmaf(omsx, ae, 1.0f);
            const float n1 = fmaf(-sx, sx, 1.0f);
            const float nump = pn * n1;
            const float nume = (sx * en) * (2.0f - sx);
            const float u   = (dp + de) - 2.0f;
            const float rpe = fmaf(u, u - 1.0f, 1.0f);
            const float a_ = nump * de;
            const float b_ = nume * dp;
            const float s2 = fmaf(a_ - b_, rpe, s);
            const float ps = a_ * rpe;
            const float s22 = s2 * s2;
            const float s24 = s22 * s22;
            const float z = c4s * s24;           // <= 0.039
            float w = fmaf(z, 15.0f / 128.0f, -5.0f / 32.0f);
            w = fmaf(z, w, 0.25f);
            const float s2z = s2 * z;
            const float perc = s2z * w;
            s = s2 - perc;
            return perc + (pn - ps);
        };

        for (int c = 0; c < NCHA; ++c) {
            while (ld_acq(&in_ready) < c + 1) {}
            const int slot = c & 3;
            const float2* ib = (const float2*)&inbuf[slot][0][0];
            float2 pe[CH];
            #pragma unroll
            for (int i = 0; i < CH; ++i) pe[i] = ib[i * 64 + lane];
            float* pb = prw + (size_t)(c * CH) * NB + b;
            #pragma unroll
            for (int i = 0; i < CH; ++i)
                pb[(size_t)i * NB] = prod_step(pe[i].x, pe[i].y);
            // fire-and-forget stores; flag guards only inbuf reuse.
            asm volatile("s_waitcnt lgkmcnt(0)" ::: "memory");
            if (lane == 0) st_rlx(&w1_done, c + 1);
        }
    }
}

// ============== kernel B: time-parallel conv + r replay ==============
__global__ __launch_bounds__(128, 1)
void gr4j_b(const float* __restrict__ prw,      // [T_TOTAL*NB] pr (ws)
            const float* __restrict__ params,   // [NB,4]
            float*       __restrict__ out)      // [(T_TOTAL-NWARM)*NB]
{
    const int lane = threadIdx.x & 63;
    const int wid  = threadIdx.x >> 6;
    const int bg   = blockIdx.x & 31;            // basin group
    const int tj   = blockIdx.x >> 5;            // time chunk 0..9
    const int b    = bg * 64 + lane;
    // warmup start / chunk counts (all multiples of 365 -> /5 exact)
    const int t_w0   = (tj <= 4) ? 0 : 365 * (tj - 4);
    const int nch    = (365 * (tj + 2) - t_w0) / CH;   // 146..438
    const int out_c0 = (365 * (tj + 1) - t_w0) / CH;   // first output chunk

    __shared__ float4 inbuf[4][CH][16];          // 5.1 KB pr ring
    __shared__ int in_ready;
    __shared__ int w1_done;
    if (threadIdx.x == 0) { in_ready = 0; w1_done = 0; }
    __syncthreads();

    if (wid == 0) {
        // w0: pr staging. 16 lanes x float4 = one 64-basin pr row (256B).
        const float4* p4 = (const float4*)prw
                         + ((size_t)t_w0 * 512 + (size_t)bg * 16 + lane);
        const bool active = (lane < 16);
        if (active) {
            #pragma unroll
            for (int cc = 0; cc < 2; ++cc)
                #pragma unroll
                for (int i = 0; i < CH; ++i)
                    gl_lds_16((const float*)(p4 + (size_t)(cc * CH + i) * 512),
                              (float*)&inbuf[cc][i][0]);
        }
        for (int c = 0; c + 3 <= nch; ++c) {
            if (c >= 2) while (ld_acq(&w1_done) < c - 1) {}
            if (active) {
                const int slot = (c + 2) & 3;
                const float4* cb = p4 + (size_t)(c + 2) * CH * 512;
                #pragma unroll
                for (int i = 0; i < CH; ++i)
                    gl_lds_16((const float*)(cb + (size_t)i * 512),
                              (float*)&inbuf[slot][i][0]);
            }
            asm volatile("s_waitcnt vmcnt(5)" ::: "memory");
            if (lane == 0) st_rlx(&in_ready, c + 2);
        }
        asm volatile("s_waitcnt vmcnt(0)" ::: "memory");
        if (lane == 0) st_rlx(&in_ready, nch);
    } else {
        // w1: conv (R12 w2 verbatim) + r-chain (R12 w3 verbatim) + store.
        const float x2 = -5.0f + params[b * 4 + 1] * 8.0f;
        const float x3 = 20.0f + params[b * 4 + 2] * 280.0f;
        const float x4 = 1.1f  + params[b * 4 + 3] * 1.8f;
        const float invx3 = __builtin_amdgcn_rcpf(x3);
        float u10, u11, u12, u20, u21, u22, u23, u24, u25;
        {
            float sh[3];
            #pragma unroll
            for (int j = 1; j <= 3; ++j)
                sh[j - 1] = powf(fminf((float)j / x4, 1.0f), 2.5f);
            u10 = sh[0] * invx3;                 // invx3 folded: ships q9/x3
            u11 = (sh[1] - sh[0]) * invx3;
            u12 = (sh[2] - sh[1]) * invx3;
            float s2h[6];
            #pragma unroll
            for (int j = 1; j <= 6; ++j) {
                float rr = (float)j / x4;
                s2h[j - 1] = ((float)j <= x4) ? 0.5f * powf(rr, 2.5f)
                           : 1.0f - 0.5f * powf(fmaxf(2.0f - rr, 0.0f), 2.5f);
            }
            u20 = s2h[0];          u21 = s2h[1] - s2h[0]; u22 = s2h[2] - s2h[1];
            u23 = s2h[3] - s2h[2]; u24 = s2h[4] - s2h[3]; u25 = s2h[5] - s2h[4];
        }
        // conv history: EXACT init from stored pr (zeros for t_w0==0).
        float ph0 = 0.f, ph1 = 0.f, ph2 = 0.f, ph3 = 0.f, ph4 = 0.f;
        if (t_w0 > 0) {
            ph0 = prw[(size_t)(t_w0 - 1) * NB + b];
            ph1 = prw[(size_t)(t_w0 - 2) * NB + b];
            ph2 = prw[(size_t)(t_w0 - 3) * NB + b];
            ph3 = prw[(size_t)(t_w0 - 4) * NB + b];
            ph4 = prw[(size_t)(t_w0 - 5) * NB + b];
        }

        auto conv_step = [&](float pr) -> float2 {
            const float q9i = fmaf(u10, pr, fmaf(u11, ph0, u12 * ph1));
            const float q1 = fmaf(u20, pr, fmaf(u21, ph0, fmaf(u22, ph1,
                             fmaf(u23, ph2, fmaf(u24, ph3, u25 * ph4)))));
            ph4 = ph3; ph3 = ph2; ph2 = ph1; ph1 = ph0; ph0 = pr;
            return make_float2(q9i, q1);
        };

        // r-chain (R12 w3_step verbatim): deg-9 (1+zt)^{-1/8} poly.
        constexpr float cf0 =  0.9358240f;
        constexpr float cf1 = -0.1169780f;
        constexpr float cf2 =  0.0658002f;
        constexpr float cf3 = -0.0466083f;
        constexpr float cf4 =  0.0364132f;
        constexpr float cf5 = -0.0300409f;
        constexpr float cf6 =  0.0256597f;
        constexpr float cf7 = -0.0224527f;
        constexpr float cf8 =  0.0199967f;
        constexpr float cf9 = -0.0180526f;
        constexpr float uscale = 0.5882353f;     // 1/1.7
        constexpr float ubias  = -0.4117647f;    // -0.7/1.7
        float rx = 0.5f;                         // r0 = 0.5*x3
        float h  = 0.70710678f;                  // sqrt(rx)

        auto w3_step = [&](float2 qin) -> float {
            const float rxpq = rx + qin.x;       // qin.x = q9/x3
            const float h4   = rx * rx;
            const float h3   = rx * h;
            const float h7   = h3 * h4;          // (r/x3)^3.5
            const float gex  = x2 * h7;
            const float rx2  = fmaf(gex, invx3, rxpq);
            const float srt  = __builtin_amdgcn_sqrtf(rx2);
            const float z2c  = rx2 * rx2;
            const float zt   = z2c * z2c;        // <= 1.4 proven
            const float u    = fmaf(zt, uscale, ubias);
            const float u2   = u * u;
            const float u4   = u2 * u2;
            const float u8   = u4 * u4;
            const float p0 = fmaf(cf1, u, cf0);
            const float p1 = fmaf(cf3, u, cf2);
            const float p2 = fmaf(cf5, u, cf4);
            const float p3 = fmaf(cf7, u, cf6);
            const float p4 = fmaf(cf9, u, cf8);
            const float q0 = fmaf(p1, u2, p0);
            const float q1p = fmaf(p3, u2, p2);
            const float r0 = fmaf(q1p, u4, q0);
            const float v  = fmaf(p4, u8, r0);   // (1+zt)^{-1/8}
            const float hn = srt * v;
            const float rxn = hn * hn;
            const float qr  = x3 * (rx2 - rxn);
            h  = hn;
            rx = rxn;
            return qr + fmaxf(0.0f, qin.y + gex);
        };

        // warmup chunks: state only (qr/qd DCE'd in discard path)
        for (int c = 0; c < out_c0; ++c) {
            while (ld_acq(&in_ready) < c + 1) {}
            // t=365 conv-history reset (reference restarts at WARMUP).
            // Only blocks with t_w0==0 contain t=365; tj=1..4 hit it here.
            if (t_w0 == 0 && c == 73) { ph0 = ph1 = ph2 = ph3 = ph4 = 0.0f; }
            const int slot = c & 3;
            const float* ib = (const float*)&inbuf[slot][0][0];
            float prr[CH];
            #pragma unroll
            for (int i = 0; i < CH; ++i) prr[i] = ib[i * 64 + lane];
            #pragma unroll
            for (int i = 0; i < CH; ++i) (void)w3_step(conv_step(prr[i]));
            asm volatile("s_waitcnt lgkmcnt(0)" ::: "memory");
            if (lane == 0) st_rlx(&w1_done, c + 1);
        }
        // output chunks: rows t_w0-365+5c .. +4 (disjoint across blocks)
        for (int c = out_c0; c < nch; ++c) {
            while (ld_acq(&in_ready) < c + 1) {}
            if (t_w0 == 0 && c == 73) { ph0 = ph1 = ph2 = ph3 = ph4 = 0.0f; }
            const int slot = c & 3;
            const float* ib = (const float*)&inbuf[slot][0][0];
            float prr[CH];
            #pragma unroll
            for (int i = 0; i < CH; ++i) prr[i] = ib[i * 64 + lane];
            float* ob = out + (size_t)(t_w0 - NWARM + c * CH) * NB + b;
            #pragma unroll
            for (int i = 0; i < CH; ++i)
                ob[(size_t)i * NB] = w3_step(conv_step(prr[i]));
            asm volatile("s_waitcnt lgkmcnt(0)" ::: "memory");
            if (lane == 0) st_rlx(&w1_done, c + 1);
        }
    }
}

extern "C" void kernel_launch(void* const* d_in, const int* in_sizes, int n_in,
                              void* d_out, int out_size, void* d_ws, size_t ws_size,
                              hipStream_t stream) {
    const float2* pe_in  = (const float2*)d_in[0];   // p_and_e [4015,2048,2]
    const float*  params = (const float*)d_in[1];    // parameters [2048,4]
    float* out = (float*)d_out;                      // [3650,2048,1]
    float* prw = (float*)d_ws;                       // pr scratch, 32.9 MB
    (void)in_sizes; (void)n_in; (void)out_size; (void)ws_size;

    gr4j_a<<<dim3(NB / 64), dim3(128), 0, stream>>>(pe_in, params, prw);
    gr4j_b<<<dim3((NB / 64) * 10), dim3(128), 0, stream>>>(prw, params, out);
}

// Round 9
// 579.908 us; speedup vs baseline: 1.1021x; 1.1021x over previous
//
#include <hip/hip_runtime.h>

// GR4J daily hydrological model, round 15: fully self-contained waves.
// T=4015 steps, WARMUP=365, B=2048 basins.
//
// R14 validated the split (absmax EXACTLY = R12's 0.0078125) but A was the
// wall: 386-454 us. Fit: time ~= insts*4.7 + (~400-cyc flag/LDS handoff)/CH.
// R15 deletes the handoff entirely: no LDS, no flags, no staging waves.
//
// Kernel A (32 blk x 64 thr, ONE wave): serial s-chain, double-banked
//   5-step register rotation (bank c+2 loaded while computing c; 10-step
//   ~700cyc lookahead), pr -> prw. Chain shortened 13->12 edges using
//   pn*en==0 (mutually exclusive): dp*de = 1+A+B EXACTLY, so
//   Delta = nump*(1-A) - nume*(1-B)   (err <= 1e-4; one term always 0)
//   s' = s2*(1 - m + 2.5 m^2), m = z/4  (drops m^3 <= 8.5e-4)
//   pr = (s2 - s') + (pn - ps).
// Kernel B (320 blk x 64 thr, ONE wave each): conv + r replay from prw,
//   W_r = 730 (R14 measured W=1825 == exact; est. residual at 730 ~1e-3):
//   tj<=1: replay from t=0, bit-exact (incl. t=365 conv reset at c==73);
//   tj==2: starts AT the reset (t_w0=365, zero history, exact);
//   tj>=3: exact conv history from prw[t_w0-5..t_w0-1], r warmed 730.
//   Warmup chunks compute q9+r only (q1/store dead-code eliminated).
//   Max 1095 steps/block (R14: 2190).
//
// A is the purest serial-chain wave possible -- its cyc/step measures the
// lone-wave cadence floor directly (model discriminator for R16).
//
// Approximations (threshold 3.97e-2; R12/R14 measured 7.8e-3):
//  - tanh(x) ~= x (x<=0.01);
//  - Delta/ps: 1/(1+u) ~= 1-u with u=A or B (err<=1e-4, exact split);
//  - perc series to m^2 (m<=0.0098; dropped 7.5m^3*s2 <= 8.5e-4);
//  - routing (1+zt)^{-1/8} deg-9 Taylor about 0.7 on [0,1.4];
//  - tj>=3 r-init after 730-step re-warmup (~1e-3).

#define T_TOTAL 4015
#define NWARM   365
#define NB      2048

// ======================= kernel A: serial s-pass =======================
__global__ __launch_bounds__(64, 1)
void gr4j_a(const float2* __restrict__ pe_in,   // [T_TOTAL*NB] (p,e)
            const float*  __restrict__ params,  // [NB,4]
            float*        __restrict__ prw)     // [T_TOTAL*NB] pr (ws)
{
    const int lane = threadIdx.x;                // 0..63
    const int b    = blockIdx.x * 64 + lane;

    const float x1    = 100.0f + params[b * 4 + 0] * 1100.0f;
    const float invx1 = __builtin_amdgcn_rcpf(x1);
    const float c49   = (4.0f / 9.0f) * invx1;
    const float c49_2 = c49 * c49;
    const float cq    = 0.25f * (c49_2 * c49_2); // m = cq*s2^4 = z/4
    float s = 0.5f * x1;

    auto step = [&](float2 pe) -> float {
        const float diff = pe.x - pe.y;
        const float pn   = fmaxf(diff, 0.0f);
        const float en   = fmaxf(-diff, 0.0f);
        const float ap   = pn * invx1;           // ~= tanh(pn/x1)
        const float ae   = en * invx1;           // ~= tanh(en/x1)
        const float sx   = s * invx1;            // [1]
        const float omsx = 1.0f - sx;            // [2]
        const float A    = sx * ap;              // [2]
        const float Bv   = omsx * ae;            // [3]
        const float n1   = fmaf(-sx, sx, 1.0f);  // [2]
        const float nump = pn * n1;              // [3]
        const float nume = (sx * en) * (2.0f - sx);  // [3]
        const float ps   = nump * (1.0f - A);    // [4]  (1/(1+A) ~= 1-A)
        const float es   = nume * (1.0f - Bv);   // [4]
        const float s2   = s + (ps - es);        // [6]
        const float s22  = s2 * s2;              // [7]
        const float s24  = s22 * s22;            // [8]
        const float m    = cq * s24;             // [9]  z/4 <= 0.0098
        const float corr = fmaf(m, fmaf(2.5f, m, -1.0f), 1.0f);  // [10,11]
        const float sn   = s2 * corr;            // [12] s2*(1-m+2.5m^2)
        const float pr   = (s2 - sn) + (pn - ps);    // off-chain
        s = sn;
        return pr;
    };

    const float2* gp = pe_in + b;
    float*        pw = prw + b;

    // double-banked rotation: bank A = even chunks, bank B = odd chunks;
    // while computing chunk c, refill same bank with chunk c+2.
    float2 bA[5], bB[5];
    #pragma unroll
    for (int i = 0; i < 5; ++i) bA[i] = gp[(size_t)i * NB];
    #pragma unroll
    for (int i = 0; i < 5; ++i) bB[i] = gp[(size_t)(5 + i) * NB];

    // 803 chunks (803*5 = 4015): pairs 0..399 full-refill, then 800..802.
    for (int cp = 0; cp < 400; ++cp) {
        const size_t tb = (size_t)cp * 10;
        #pragma unroll
        for (int i = 0; i < 5; ++i) {            // chunk 2cp  (bank A)
            const float2 pe = bA[i];
            bA[i] = gp[(tb + 10 + i) * NB];
            pw[(tb + i) * NB] = step(pe);
        }
        #pragma unroll
        for (int i = 0; i < 5; ++i) {            // chunk 2cp+1 (bank B)
            const float2 pe = bB[i];
            bB[i] = gp[(tb + 15 + i) * NB];
            pw[(tb + 5 + i) * NB] = step(pe);
        }
    }
    #pragma unroll
    for (int i = 0; i < 5; ++i) {                // c=800 (A), refill 802
        const float2 pe = bA[i];
        bA[i] = gp[(size_t)(4010 + i) * NB];
        pw[(size_t)(4000 + i) * NB] = step(pe);
    }
    #pragma unroll
    for (int i = 0; i < 5; ++i)                  // c=801 (B), no refill
        pw[(size_t)(4005 + i) * NB] = step(bB[i]);
    #pragma unroll
    for (int i = 0; i < 5; ++i)                  // c=802 (A), no refill
        pw[(size_t)(4010 + i) * NB] = step(bA[i]);
}

// ============== kernel B: time-parallel conv + r replay ==============
__global__ __launch_bounds__(64, 1)
void gr4j_b(const float* __restrict__ prw,      // [T_TOTAL*NB] pr (ws)
            const float* __restrict__ params,   // [NB,4]
            float*       __restrict__ out)      // [(T_TOTAL-NWARM)*NB]
{
    const int lane = threadIdx.x;
    const int bg   = blockIdx.x & 31;            // basin group 0..31
    const int tj   = blockIdx.x >> 5;            // time chunk 0..9
    const int b    = bg * 64 + lane;
    const int t_w0 = (tj <= 1) ? 0 : 365 * (tj - 1);
    const int nch  = (365 * (tj + 2) - t_w0) / 5;    // 146 (tj=0) or 219
    const int och0 = nch - 73;                   // first output chunk

    const float x2 = -5.0f + params[b * 4 + 1] * 8.0f;
    const float x3 = 20.0f + params[b * 4 + 2] * 280.0f;
    const float x4 = 1.1f  + params[b * 4 + 3] * 1.8f;
    const float invx3 = __builtin_amdgcn_rcpf(x3);

    float u10, u11, u12, u20, u21, u22, u23, u24, u25;
    {
        float sh[3];
        #pragma unroll
        for (int j = 1; j <= 3; ++j)
            sh[j - 1] = powf(fminf((float)j / x4, 1.0f), 2.5f);
        u10 = sh[0] * invx3;                     // ships q9/x3 directly
        u11 = (sh[1] - sh[0]) * invx3;
        u12 = (sh[2] - sh[1]) * invx3;
        float s2h[6];
        #pragma unroll
        for (int j = 1; j <= 6; ++j) {
            float rr = (float)j / x4;
            s2h[j - 1] = ((float)j <= x4) ? 0.5f * powf(rr, 2.5f)
                       : 1.0f - 0.5f * powf(fmaxf(2.0f - rr, 0.0f), 2.5f);
        }
        u20 = s2h[0];          u21 = s2h[1] - s2h[0]; u22 = s2h[2] - s2h[1];
        u23 = s2h[3] - s2h[2]; u24 = s2h[4] - s2h[3]; u25 = s2h[5] - s2h[4];
    }

    // conv history: exact. t_w0==0/365 -> zeros (reference zero-init /
    // reset at t=365); t_w0>365 -> taps from prw.
    float ph0 = 0.f, ph1 = 0.f, ph2 = 0.f, ph3 = 0.f, ph4 = 0.f;
    if (t_w0 > 365) {
        ph0 = prw[(size_t)(t_w0 - 1) * NB + b];
        ph1 = prw[(size_t)(t_w0 - 2) * NB + b];
        ph2 = prw[(size_t)(t_w0 - 3) * NB + b];
        ph3 = prw[(size_t)(t_w0 - 4) * NB + b];
        ph4 = prw[(size_t)(t_w0 - 5) * NB + b];
    }

    // r-chain (R12 w3_step): deg-9 (1+zt)^{-1/8} poly, zt<=1.4 proven.
    constexpr float cf0 =  0.9358240f;
    constexpr float cf1 = -0.1169780f;
    constexpr float cf2 =  0.0658002f;
    constexpr float cf3 = -0.0466083f;
    constexpr float cf4 =  0.0364132f;
    constexpr float cf5 = -0.0300409f;
    constexpr float cf6 =  0.0256597f;
    constexpr float cf7 = -0.0224527f;
    constexpr float cf8 =  0.0199967f;
    constexpr float cf9 = -0.0180526f;
    constexpr float uscale = 0.5882353f;         // 1/1.7
    constexpr float ubias  = -0.4117647f;        // -0.7/1.7
    float rx = 0.5f;                             // r0 = 0.5*x3
    float h  = 0.70710678f;                      // sqrt(rx)

    auto w3_step = [&](float q9i, float q1) -> float {
        const float rxpq = rx + q9i;
        const float h4   = rx * rx;
        const float h3   = rx * h;
        const float h7   = h3 * h4;              // (r/x3)^3.5
        const float gex  = x2 * h7;
        const float rx2  = fmaf(gex, invx3, rxpq);
        const float srt  = __builtin_amdgcn_sqrtf(rx2);
        const float z2c  = rx2 * rx2;
        const float zt   = z2c * z2c;
        const float u    = fmaf(zt, uscale, ubias);
        const float u2   = u * u;
        const float u4   = u2 * u2;
        const float u8   = u4 * u4;
        const float p0 = fmaf(cf1, u, cf0);
        const float p1 = fmaf(cf3, u, cf2);
        const float p2 = fmaf(cf5, u, cf4);
        const float p3 = fmaf(cf7, u, cf6);
        const float p4 = fmaf(cf9, u, cf8);
        const float q0 = fmaf(p1, u2, p0);
        const float q1p = fmaf(p3, u2, p2);
        const float r0 = fmaf(q1p, u4, q0);
        const float v  = fmaf(p4, u8, r0);       // (1+zt)^{-1/8}
        const float hn = srt * v;
        const float rxn = hn * hn;
        const float qr  = x3 * (rx2 - rxn);
        h  = hn;
        rx = rxn;
        return qr + fmaxf(0.0f, q1 + gex);
    };

    const float* pp = prw + (size_t)t_w0 * NB + b;

    float rA[5], rB[5];
    #pragma unroll
    for (int i = 0; i < 5; ++i) rA[i] = pp[(size_t)i * NB];
    #pragma unroll
    for (int i = 0; i < 5; ++i) rB[i] = pp[(size_t)(5 + i) * NB];

    auto chunk = [&](float (&rot)[5], int c) {
        // t=365 conv-history reset for t_w0==0 blocks (tj 0,1): local==global.
        if (t_w0 == 0 && c == 73) { ph0 = ph1 = ph2 = ph3 = ph4 = 0.0f; }
        const bool rf = (c + 2 < nch);
        const size_t tb = (size_t)c * 5;
        if (c < och0) {
            // warmup: q9 + r state only (q1/qr/qd dead-code eliminated)
            #pragma unroll
            for (int i = 0; i < 5; ++i) {
                const float pr = rot[i];
                if (rf) rot[i] = pp[(tb + 10 + i) * NB];
                const float q9i = fmaf(u10, pr, fmaf(u11, ph0, u12 * ph1));
                ph4 = ph3; ph3 = ph2; ph2 = ph1; ph1 = ph0; ph0 = pr;
                (void)w3_step(q9i, 0.0f);
            }
        } else {
            float* obc = out + (size_t)(t_w0 + tb - NWARM) * NB + b;
            #pragma unroll
            for (int i = 0; i < 5; ++i) {
                const float pr = rot[i];
                if (rf) rot[i] = pp[(tb + 10 + i) * NB];
                const float q9i = fmaf(u10, pr, fmaf(u11, ph0, u12 * ph1));
                const float q1 = fmaf(u20, pr, fmaf(u21, ph0, fmaf(u22, ph1,
                                 fmaf(u23, ph2, fmaf(u24, ph3, u25 * ph4)))));
                ph4 = ph3; ph3 = ph2; ph2 = ph1; ph1 = ph0; ph0 = pr;
                obc[(size_t)i * NB] = w3_step(q9i, q1);
            }
        }
    };

    int c = 0;
    while (true) {
        chunk(rA, c);
        if (++c == nch) break;
        chunk(rB, c);
        if (++c == nch) break;
    }
}

extern "C" void kernel_launch(void* const* d_in, const int* in_sizes, int n_in,
                              void* d_out, int out_size, void* d_ws, size_t ws_size,
                              hipStream_t stream) {
    const float2* pe_in  = (const float2*)d_in[0];   // p_and_e [4015,2048,2]
    const float*  params = (const float*)d_in[1];    // parameters [2048,4]
    float* out = (float*)d_out;                      // [3650,2048,1]
    float* prw = (float*)d_ws;                       // pr scratch, 32.9 MB
    (void)in_sizes; (void)n_in; (void)out_size; (void)ws_size;

    gr4j_a<<<dim3(NB / 64), dim3(64), 0, stream>>>(pe_in, params, prw);
    gr4j_b<<<dim3((NB / 64) * 10), dim3(64), 0, stream>>>(prw, params, out);
}